// Round 3
// baseline (385.724 us; speedup 1.0000x reference)
//
#include <hip/hip_runtime.h>

// UWNeRF RGB renderer: R rays x S=128 samples, fp32.
// R2 post-mortem: bound on L1/TA line transactions (R1 & R2: identical
// ~19.9M line touches, identical dur; VALU/DS far from saturated).
// R3: stage the 4 [S,3] channel arrays through LDS with global_load_lds
// width-16 DMA (contiguous, 1 touch/line) -> 2.7x fewer L1 transactions.
// Compute structure unchanged from R2: 32 lanes/ray, 4 samples/lane,
// register prefix + width-32 shuffle scan + butterfly reduction.

constexpr int S  = 128;
constexpr int RB = 8;               // rays per block
constexpr int F3 = 3 * S;           // 384 floats per ray per channel array
constexpr int CH = RB * F3;         // 3072 floats per array per block

__global__ __launch_bounds__(256, 3) void uwnerf_render(
    const float* __restrict__ densities,   // [R,S,1]
    const float* __restrict__ rgbs,        // [R,S,3]
    const float* __restrict__ veil,        // [R,S,3]
    const float* __restrict__ dcoef,       // [R,S,3]
    const float* __restrict__ bcoef,       // [R,S,3]
    const float* __restrict__ deltas,      // [R,S,1]
    float* __restrict__ out,               // [4,R,3]
    int R)
{
    __shared__ float lds[4 * CH];   // 49152 B -> 3 blocks/CU

    const int tid  = threadIdx.x;
    const int w    = tid >> 6;      // wave id 0..3
    const int lane = tid & 63;
    const int l    = lane & 31;     // lane within ray
    const int sub  = lane >> 5;     // ray slot within wave
    const int rb0  = blockIdx.x * RB;

    // ---- DMA stage: wave w stages channel array w for all 8 rays ----
    const float* gsrc = (w == 0) ? rgbs : (w == 1) ? veil : (w == 2) ? dcoef : bcoef;
    const size_t arrBase  = (size_t)rb0 * F3;
    const size_t maxStart = (size_t)R * F3 - 256;   // tail clamp (dup reads ok)
#pragma unroll
    for (int i = 0; i < 12; ++i) {
        size_t start = arrBase + (size_t)i * 256;
        if (start > maxStart) start = maxStart;
        __builtin_amdgcn_global_load_lds(
            (const __attribute__((address_space(1))) void*)(gsrc + start + (size_t)lane * 4),
            (__attribute__((address_space(3))) void*)(lds + w * CH + i * 256),
            16, 0, 0);
    }
    __syncthreads();   // drains vmcnt before any ds_read

    const int rr = 2 * w + sub;          // ray slot in block
    const int r  = rb0 + rr;
    if (r >= R) return;

    // ---- scalar arrays: direct coalesced float4 loads ----
    const size_t b1 = (size_t)r * S + 4 * (size_t)l;
    const float4 den4 = *(const float4*)(densities + b1);
    const float4 dlt4 = *(const float4*)(deltas + b1);

    // ---- channel fragments from LDS (48 B/lane, ds_read_b128 x3 each) ----
    const int cbase = rr * F3 + 12 * l;
    float rgbv[12], vlv[12], dcv[12], bcv[12];
#pragma unroll
    for (int i = 0; i < 3; ++i) {
        *(float4*)(rgbv + 4 * i) = *(const float4*)(lds + 0 * CH + cbase + 4 * i);
        *(float4*)(vlv  + 4 * i) = *(const float4*)(lds + 1 * CH + cbase + 4 * i);
        *(float4*)(dcv  + 4 * i) = *(const float4*)(lds + 2 * CH + cbase + 4 * i);
        *(float4*)(bcv  + 4 * i) = *(const float4*)(lds + 3 * CH + cbase + 4 * i);
    }

    const float dl[4] = {dlt4.x, dlt4.y, dlt4.z, dlt4.w};
    const float dn[4] = {den4.x, den4.y, den4.z, den4.w};

    // local exclusive prefixes (per-lane, registers)
    float odd[4], cumO[4];
    float accO = 0.0f;
#pragma unroll
    for (int s = 0; s < 4; ++s) {
        odd[s] = dl[s] * dn[s];
        cumO[s] = accO;
        accO += odd[s];
    }

    float cumD[12], cumB[12], loc[7];
    loc[0] = accO;
#pragma unroll
    for (int c = 0; c < 3; ++c) {
        float ad = 0.0f, ab = 0.0f;
#pragma unroll
        for (int s = 0; s < 4; ++s) {
            const float dv = dl[s] * dcv[3 * s + c];
            const float bv = dl[s] * bcv[3 * s + c];
            cumD[4 * c + s] = ad; ad += dv;
            cumB[4 * c + s] = ab; ab += bv;
        }
        loc[1 + c] = ad;
        loc[4 + c] = ab;
    }

    // width-32 inclusive scan of 7 lane-aggregates
    float agg[7];
#pragma unroll
    for (int j = 0; j < 7; ++j) agg[j] = loc[j];
#pragma unroll
    for (int off = 1; off < 32; off <<= 1) {
        float t[7];
#pragma unroll
        for (int j = 0; j < 7; ++j) t[j] = __shfl_up(agg[j], off, 32);
        const bool p = (l >= off);
#pragma unroll
        for (int j = 0; j < 7; ++j) agg[j] += p ? t[j] : 0.0f;
    }
    float Lex[7];
#pragma unroll
    for (int j = 0; j < 7; ++j) Lex[j] = agg[j] - loc[j];

    // object transmittance / weights
    float t_[4], T_[4], w_[4];
#pragma unroll
    for (int s = 0; s < 4; ++s) t_[s] = __expf(-odd[s]);
    T_[0] = __expf(-Lex[0]);
#pragma unroll
    for (int s = 1; s < 4; ++s) T_[s] = T_[s - 1] * t_[s - 1];
#pragma unroll
    for (int s = 0; s < 4; ++s) w_[s] = (1.0f - t_[s]) * T_[s];

    // partials: [0..2] restored, [3..5] direct, [6..8] backscatter_obj, [9] wsum
    float red[10];
    red[9] = w_[0] + w_[1] + w_[2] + w_[3];
#pragma unroll
    for (int c = 0; c < 3; ++c) {
        const float BD = Lex[0] + Lex[1 + c];
        const float BB = Lex[0] + Lex[4 + c];
        float sr = 0.0f, sd = 0.0f, sb = 0.0f;
#pragma unroll
        for (int s = 0; s < 4; ++s) {
            const float g = rgbv[3 * s + c];
            const float v = vlv[3 * s + c];
            const float omt = 1.0f - t_[s];
            const float wda = omt * __expf(-(BD + cumO[s] + cumD[4 * c + s]));
            const float wbt = omt * __expf(-(BB + cumO[s] + cumB[4 * c + s]));
            sr += w_[s] * g;
            sd += wda * g;
            sb += (w_[s] - wbt) * v;
        }
        red[c] = sr;
        red[3 + c] = sd;
        red[6 + c] = sb;
    }

    // butterfly within each 32-lane half
#pragma unroll
    for (int off = 16; off >= 1; off >>= 1) {
#pragma unroll
        for (int j = 0; j < 10; ++j) red[j] += __shfl_xor(red[j], off, 64);
    }

    // veiling_light at sample 0: straight LDS broadcast read
    float vl0[3];
#pragma unroll
    for (int c = 0; c < 3; ++c) vl0[c] = lds[1 * CH + rr * F3 + c];

    if (l < 3) {
        const int c = l;
        const float mask = fminf(fmaxf(red[9], 0.0f), 1.0f);
        const float bsr  = red[6 + c] + (1.0f - mask) * vl0[c];
        const size_t rc = (size_t)r * 3 + c;
        const size_t stride = (size_t)R * 3;
        out[rc]              = fminf(fmaxf(red[3 + c] + bsr, 0.0f), 1.0f); // rgb
        out[stride + rc]     = fminf(fmaxf(red[c],          0.0f), 1.0f); // restored
        out[2 * stride + rc] = fminf(fmaxf(red[3 + c],      0.0f), 1.0f); // direct
        out[3 * stride + rc] = fminf(fmaxf(bsr,             0.0f), 1.0f); // backscatter
    }
}

extern "C" void kernel_launch(void* const* d_in, const int* in_sizes, int n_in,
                              void* d_out, int out_size, void* d_ws, size_t ws_size,
                              hipStream_t stream) {
    const float* densities = (const float*)d_in[0];
    const float* rgbs      = (const float*)d_in[1];
    const float* veil      = (const float*)d_in[2];
    const float* dcoef     = (const float*)d_in[3];
    const float* bcoef     = (const float*)d_in[4];
    const float* deltas    = (const float*)d_in[5];
    float* out = (float*)d_out;

    const int R = in_sizes[0] / S;   // 65536
    dim3 grid((R + RB - 1) / RB), block(256);
    uwnerf_render<<<grid, block, 0, stream>>>(densities, rgbs, veil, dcoef, bcoef,
                                              deltas, out, R);
}